// Round 3
// baseline (3064.563 us; speedup 1.0000x reference)
//
#include <hip/hip_runtime.h>

#define DFEAT 128

// deg[i] = 1.0 (self loop fill weight, renorm trick)
__global__ void deg_init_kernel(float* deg, int n) {
    int i = blockIdx.x * blockDim.x + threadIdx.x;
    if (i < n) deg[i] = 1.0f;
}

// deg[row[e]] += w[e]
__global__ void deg_accum_kernel(const int* __restrict__ rows,
                                 const float* __restrict__ ew,
                                 float* __restrict__ deg, int E) {
    int e = blockIdx.x * blockDim.x + threadIdx.x;
    if (e < E) atomicAdd(&deg[rows[e]], ew[e]);
}

// deg -> d^{-1/2}
__global__ void dinv_kernel(float* deg, int n) {
    int i = blockIdx.x * blockDim.x + threadIdx.x;
    if (i < n) {
        float d = deg[i];
        deg[i] = (d > 0.0f) ? rsqrtf(d) : 0.0f;
    }
}

// a[i][j] = dinv[i]^2 * x[i][j]   (self-loop term, written into d_out)
__global__ void agg_init_kernel(const float* __restrict__ x,
                                const float* __restrict__ dinv,
                                float* __restrict__ a, long long total) {
    long long idx = (long long)blockIdx.x * blockDim.x + threadIdx.x;
    if (idx < total) {
        int row = (int)(idx >> 7);
        float di = dinv[row];
        a[idx] = di * di * x[idx];
    }
}

// per-edge scatter in x-space: a[row] += w*dinv[row]*dinv[col] * x[col]
// 32 lanes per edge, float4 per lane
__global__ void edge_agg_kernel(const int* __restrict__ rows,
                                const int* __restrict__ cols,
                                const float* __restrict__ ew,
                                const float* __restrict__ dinv,
                                const float* __restrict__ x,
                                float* __restrict__ a, int E) {
    long long t = (long long)blockIdx.x * blockDim.x + threadIdx.x;
    int e = (int)(t >> 5);
    int lane = (int)(t & 31);
    if (e >= E) return;
    int r = rows[e];
    int c = cols[e];
    float w = ew[e] * dinv[r] * dinv[c];
    float4 v = reinterpret_cast<const float4*>(x + (long long)c * DFEAT)[lane];
    float* arow = a + (long long)r * DFEAT + lane * 4;
    atomicAdd(arow + 0, w * v.x);
    atomicAdd(arow + 1, w * v.y);
    atomicAdd(arow + 2, w * v.z);
    atomicAdd(arow + 3, w * v.w);
}

// in-place: out_row = a_row @ K + bias    (K staged in LDS, rows staged in LDS)
__global__ __launch_bounds__(256) void gemm_inplace_kernel(float* __restrict__ a,
                                                           const float* __restrict__ w,
                                                           const float* __restrict__ bias,
                                                           int n) {
    __shared__ float klds[DFEAT * DFEAT];   // 64 KB
    __shared__ float rowbuf[2 * DFEAT];     // 1 KB, two rows per iter
    for (int i = threadIdx.x; i < DFEAT * DFEAT; i += 256) klds[i] = w[i];

    int col = threadIdx.x & 127;
    int sub = threadIdx.x >> 7;             // 0..1
    float b = bias[col];
    __syncthreads();

    for (long long row0 = (long long)blockIdx.x * 2; row0 < n;
         row0 += (long long)gridDim.x * 2) {
        // stage both rows into LDS (256 threads load 256 floats)
        long long gidx = row0 * DFEAT + threadIdx.x;
        if (gidx < (long long)n * DFEAT)
            rowbuf[threadIdx.x] = a[gidx];
        __syncthreads();

        long long row = row0 + sub;
        if (row < n) {
            const float* rb = rowbuf + sub * DFEAT;
            float acc = b;
            #pragma unroll
            for (int k = 0; k < DFEAT; k += 4) {
                acc += rb[k + 0] * klds[(k + 0) * DFEAT + col];
                acc += rb[k + 1] * klds[(k + 1) * DFEAT + col];
                acc += rb[k + 2] * klds[(k + 2) * DFEAT + col];
                acc += rb[k + 3] * klds[(k + 3) * DFEAT + col];
            }
            a[row * DFEAT + col] = acc;     // safe: row fully staged in LDS
        }
        __syncthreads();                    // protect rowbuf for next iter
    }
}

extern "C" void kernel_launch(void* const* d_in, const int* in_sizes, int n_in,
                              void* d_out, int out_size, void* d_ws, size_t ws_size,
                              hipStream_t stream) {
    const float* x    = (const float*)d_in[0];
    const int*   ei   = (const int*)d_in[1];    // int32 per harness convention!
    const float* ew   = (const float*)d_in[2];
    const float* wm   = (const float*)d_in[3];
    const float* bias = (const float*)d_in[4];
    float* out = (float*)d_out;                 // doubles as the aggregation buffer

    const int n = in_sizes[0] / DFEAT;          // 100000
    const int E = in_sizes[1] / 2;              // 1600000
    const int* rows = ei;                       // edge_index[0]
    const int* cols = ei + E;                   // edge_index[1]

    float* dinv = (float*)d_ws;                 // n floats = 400 KB only

    // 1. degree -> d^{-1/2}
    deg_init_kernel<<<(n + 255) / 256, 256, 0, stream>>>(dinv, n);
    deg_accum_kernel<<<(E + 255) / 256, 256, 0, stream>>>(rows, ew, dinv, E);
    dinv_kernel<<<(n + 255) / 256, 256, 0, stream>>>(dinv, n);

    // 2. aggregation in x-space, into d_out
    long long total = (long long)n * DFEAT;
    agg_init_kernel<<<(int)((total + 255) / 256), 256, 0, stream>>>(x, dinv, out, total);
    long long tthreads = (long long)E * 32;
    edge_agg_kernel<<<(int)((tthreads + 255) / 256), 256, 0, stream>>>(rows, cols, ew, dinv, x, out, E);

    // 3. in-place dense transform + bias
    gemm_inplace_kernel<<<2048, 256, 0, stream>>>(out, wm, bias, n);
}

// Round 7
// 748.799 us; speedup vs baseline: 4.0926x; 4.0926x over previous
//
#include <hip/hip_runtime.h>

#define DFEAT 128
#define SCAN_THREADS 1024

// ---------- CSR pipeline ----------

// deg[i]=1 (self-loop fill weight), cnt[i]=0
__global__ void init_nodes_kernel(float* deg, int* cnt, int n) {
    int i = blockIdx.x * blockDim.x + threadIdx.x;
    if (i < n) { deg[i] = 1.0f; cnt[i] = 0; }
}

// histogram of rows + weighted degree
__global__ void edge_hist_kernel(const int* __restrict__ rows,
                                 const float* __restrict__ ew,
                                 float* __restrict__ deg,
                                 int* __restrict__ cnt, int E) {
    int e = blockIdx.x * blockDim.x + threadIdx.x;
    if (e < E) {
        int r = rows[e];
        atomicAdd(&deg[r], ew[e]);
        atomicAdd(&cnt[r], 1);
    }
}

// deg -> d^{-1/2}
__global__ void dinv_kernel(float* deg, int n) {
    int i = blockIdx.x * blockDim.x + threadIdx.x;
    if (i < n) {
        float d = deg[i];
        deg[i] = (d > 0.0f) ? rsqrtf(d) : 0.0f;
    }
}

// single-block exclusive scan: cnt -> row_ptr (n+1), wptr copy
__global__ __launch_bounds__(SCAN_THREADS) void scan_kernel(const int* __restrict__ cnt,
                                                            int* __restrict__ row_ptr,
                                                            int* __restrict__ wptr, int n) {
    __shared__ int sums[SCAN_THREADS];
    int t = threadIdx.x;
    int chunk = (n + SCAN_THREADS - 1) / SCAN_THREADS;
    int lo = t * chunk;
    int hi = min(lo + chunk, n);
    int s = 0;
    for (int i = lo; i < hi; ++i) s += cnt[i];
    sums[t] = s;
    __syncthreads();
    int v = s;
    for (int off = 1; off < SCAN_THREADS; off <<= 1) {
        int u = (t >= off) ? sums[t - off] : 0;
        __syncthreads();
        v += u;
        sums[t] = v;
        __syncthreads();
    }
    int base = v - s;  // exclusive prefix of this chunk
    for (int i = lo; i < hi; ++i) {
        row_ptr[i] = base;
        wptr[i] = base;
        base += cnt[i];
    }
    if (t == SCAN_THREADS - 1) row_ptr[n] = base;  // == E
}

// scatter edges into CSR order; pack (col, norm_w) into float2
__global__ void scatter_kernel(const int* __restrict__ rows,
                               const int* __restrict__ cols,
                               const float* __restrict__ ew,
                               const float* __restrict__ dinv,
                               int* __restrict__ wptr,
                               float2* __restrict__ epak, int E) {
    int e = blockIdx.x * blockDim.x + threadIdx.x;
    if (e >= E) return;
    int r = rows[e];
    int c = cols[e];
    int pos = atomicAdd(&wptr[r], 1);
    float w = ew[e] * dinv[r] * dinv[c];
    epak[pos] = make_float2(__int_as_float(c), w);
}

// per-row gather: 32 lanes per row (float4 each), 8 rows per 256-block
__global__ __launch_bounds__(256) void row_agg_kernel(const int* __restrict__ row_ptr,
                                                      const float2* __restrict__ epak,
                                                      const float* __restrict__ dinv,
                                                      const float* __restrict__ x,
                                                      float* __restrict__ out, int n) {
    int lane = threadIdx.x & 31;
    int sub  = threadIdx.x >> 5;               // 0..7
    int r = blockIdx.x * 8 + sub;
    if (r >= n) return;
    int beg = row_ptr[r];
    int end = row_ptr[r + 1];
    float di = dinv[r];
    float w0 = di * di;                        // self-loop norm weight
    float4 acc = reinterpret_cast<const float4*>(x + (long long)r * DFEAT)[lane];
    acc.x *= w0; acc.y *= w0; acc.z *= w0; acc.w *= w0;
    for (int j = beg; j < end; ++j) {
        float2 p = epak[j];
        int c = __float_as_int(p.x);
        float w = p.y;
        float4 v = reinterpret_cast<const float4*>(x + (long long)c * DFEAT)[lane];
        acc.x += w * v.x; acc.y += w * v.y; acc.z += w * v.z; acc.w += w * v.w;
    }
    reinterpret_cast<float4*>(out + (long long)r * DFEAT)[lane] = acc;
}

// ---------- fallback (atomic scatter) if ws too small ----------

__global__ void agg_init_kernel(const float* __restrict__ x,
                                const float* __restrict__ dinv,
                                float* __restrict__ a, long long total) {
    long long idx = (long long)blockIdx.x * blockDim.x + threadIdx.x;
    if (idx < total) {
        int row = (int)(idx >> 7);
        float di = dinv[row];
        a[idx] = di * di * x[idx];
    }
}

__global__ void edge_agg_kernel(const int* __restrict__ rows,
                                const int* __restrict__ cols,
                                const float* __restrict__ ew,
                                const float* __restrict__ dinv,
                                const float* __restrict__ x,
                                float* __restrict__ a, int E) {
    long long t = (long long)blockIdx.x * blockDim.x + threadIdx.x;
    int e = (int)(t >> 5);
    int lane = (int)(t & 31);
    if (e >= E) return;
    int r = rows[e];
    int c = cols[e];
    float w = ew[e] * dinv[r] * dinv[c];
    float4 v = reinterpret_cast<const float4*>(x + (long long)c * DFEAT)[lane];
    float* arow = a + (long long)r * DFEAT + lane * 4;
    atomicAdd(arow + 0, w * v.x);
    atomicAdd(arow + 1, w * v.y);
    atomicAdd(arow + 2, w * v.z);
    atomicAdd(arow + 3, w * v.w);
}

// ---------- in-place GEMM: out = out @ K + bias ----------
// 32 rows per block, each thread: 4 cols (float4) x 4 rows register tile.
__global__ __launch_bounds__(256) void gemm_inplace_kernel(float* __restrict__ a,
                                                           const float* __restrict__ w,
                                                           const float* __restrict__ bias,
                                                           int n) {
    __shared__ float klds[DFEAT * DFEAT];      // 64 KB
    __shared__ float rowbuf[32 * DFEAT];       // 16 KB
    for (int i = threadIdx.x; i < DFEAT * DFEAT / 4; i += 256)
        reinterpret_cast<float4*>(klds)[i] = reinterpret_cast<const float4*>(w)[i];

    int col4 = threadIdx.x & 31;               // float4 column group
    int sub  = threadIdx.x >> 5;               // 0..7 -> rows sub*4..sub*4+3
    float4 b = reinterpret_cast<const float4*>(bias)[col4];

    long long row0 = (long long)blockIdx.x * 32;
    long long nf = (long long)n * DFEAT;

    // stage 32 rows (4096 floats = 1024 float4)
    {
        long long base4 = row0 * DFEAT / 4;
        for (int i = threadIdx.x; i < 32 * DFEAT / 4; i += 256) {
            if ((base4 + i) * 4 < nf)
                reinterpret_cast<float4*>(rowbuf)[i] =
                    reinterpret_cast<const float4*>(a)[base4 + i];
        }
    }
    __syncthreads();

    const float* rb = rowbuf + sub * 4 * DFEAT;
    float4 acc0 = b, acc1 = b, acc2 = b, acc3 = b;
    #pragma unroll 4
    for (int k = 0; k < DFEAT; ++k) {
        float4 kv = *reinterpret_cast<const float4*>(&klds[k * DFEAT + col4 * 4]);
        float r0 = rb[0 * DFEAT + k];
        float r1 = rb[1 * DFEAT + k];
        float r2 = rb[2 * DFEAT + k];
        float r3 = rb[3 * DFEAT + k];
        acc0.x += r0 * kv.x; acc0.y += r0 * kv.y; acc0.z += r0 * kv.z; acc0.w += r0 * kv.w;
        acc1.x += r1 * kv.x; acc1.y += r1 * kv.y; acc1.z += r1 * kv.z; acc1.w += r1 * kv.w;
        acc2.x += r2 * kv.x; acc2.y += r2 * kv.y; acc2.z += r2 * kv.z; acc2.w += r2 * kv.w;
        acc3.x += r3 * kv.x; acc3.y += r3 * kv.y; acc3.z += r3 * kv.z; acc3.w += r3 * kv.w;
    }

    long long r0 = row0 + sub * 4;
    #pragma unroll
    for (int i = 0; i < 4; ++i) {
        long long rr = r0 + i;
        if (rr < n) {
            float4 v = (i == 0) ? acc0 : (i == 1) ? acc1 : (i == 2) ? acc2 : acc3;
            reinterpret_cast<float4*>(a + rr * DFEAT)[col4] = v;
        }
    }
}

extern "C" void kernel_launch(void* const* d_in, const int* in_sizes, int n_in,
                              void* d_out, int out_size, void* d_ws, size_t ws_size,
                              hipStream_t stream) {
    const float* x    = (const float*)d_in[0];
    const int*   ei   = (const int*)d_in[1];    // int32 per harness convention
    const float* ew   = (const float*)d_in[2];
    const float* wm   = (const float*)d_in[3];
    const float* bias = (const float*)d_in[4];
    float* out = (float*)d_out;

    const int n = in_sizes[0] / DFEAT;          // 100000
    const int E = in_sizes[1] / 2;              // 1600000
    const int* rows = ei;
    const int* cols = ei + E;

    // workspace layout (16B aligned blocks)
    float*  dinv    = (float*)d_ws;                    // n
    int*    cnt     = (int*)(dinv + n);                // n
    int*    row_ptr = cnt + n;                         // n+1 (pad to n+4)
    int*    wptr    = row_ptr + (n + 4);               // n
    float2* epak    = (float2*)(wptr + n);             // E
    size_t needed = (size_t)(4LL * (3 * n + (n + 4))) + (size_t)E * 8;

    if (ws_size >= needed) {
        // CSR path
        init_nodes_kernel<<<(n + 255) / 256, 256, 0, stream>>>(dinv, cnt, n);
        edge_hist_kernel<<<(E + 255) / 256, 256, 0, stream>>>(rows, ew, dinv, cnt, E);
        dinv_kernel<<<(n + 255) / 256, 256, 0, stream>>>(dinv, n);
        scan_kernel<<<1, SCAN_THREADS, 0, stream>>>(cnt, row_ptr, wptr, n);
        scatter_kernel<<<(E + 255) / 256, 256, 0, stream>>>(rows, cols, ew, dinv, wptr, epak, E);
        row_agg_kernel<<<(n + 7) / 8, 256, 0, stream>>>(row_ptr, epak, dinv, x, out, n);
    } else {
        // fallback: atomic scatter (round-3 behavior)
        init_nodes_kernel<<<(n + 255) / 256, 256, 0, stream>>>(dinv, cnt, n);
        edge_hist_kernel<<<(E + 255) / 256, 256, 0, stream>>>(rows, ew, dinv, cnt, E);
        dinv_kernel<<<(n + 255) / 256, 256, 0, stream>>>(dinv, n);
        long long total = (long long)n * DFEAT;
        agg_init_kernel<<<(int)((total + 255) / 256), 256, 0, stream>>>(x, dinv, out, total);
        long long tthreads = (long long)E * 32;
        edge_agg_kernel<<<(int)((tthreads + 255) / 256), 256, 0, stream>>>(rows, cols, ew, dinv, x, out, E);
    }

    // in-place dense transform + bias (n divisible by 32 -> exact grid)
    gemm_inplace_kernel<<<(n + 31) / 32, 256, 0, stream>>>(out, wm, bias, n);
}